// Round 7
// baseline (210.517 us; speedup 1.0000x reference)
//
#include <hip/hip_runtime.h>

typedef __attribute__((ext_vector_type(8))) _Float16 f16x8;
typedef __attribute__((ext_vector_type(4))) _Float16 f16x4;
typedef __attribute__((ext_vector_type(4))) float f32x4;

#define T_STEPS 49
#define BM 16
#define OUTSTRIDE (4096*64)
#define YSTR 132   // f16/row: 264B = 66 dw == 2 mod 8 -> write rows 4g+i spread 8g across banks
#define HSTR 260   // f16/row: 520B = 130 dw == 2 mod 8 -> same

__device__ __forceinline__ float fast_tanh(float x) {
  float e = __builtin_amdgcn_exp2f(x * 2.885390081777927f);
  return 1.f - 2.f * __builtin_amdgcn_rcpf(e + 1.f);
}
__device__ __forceinline__ f16x8 ld_frag(const _Float16* p) {
  f16x4 a = *(const f16x4*)p;        // rows 8B-aligned
  f16x4 b = *(const f16x4*)(p + 4);
  return __builtin_shufflevector(a, b, 0,1,2,3,4,5,6,7);
}
// Workaround for backend bug: v_add/sub with two SGPR srcs violates the
// constant-bus limit. Force the subtraction through VGPRs.
__device__ __forceinline__ float vsub(float a, float b) {
  float r;
  asm("v_sub_f32 %0, %1, %2" : "=v"(r) : "v"(a), "v"(b));
  return r;
}

// 4-wave WG (256 thr), BM=16 rows, grid = 512 WGs = 2 WGs/CU: two independent
// barrier groups per CU dephase so barrier drains of one WG overlap compute of
// the other (same total MFMA/VALU/LDS work per CU as the 8-wave version).
// Wave w owns H cols [64w,64w+64) (4 tiles) in layer 1 and K cols [32w,32w+32)
// (2 tiles) in layer 2. Weights register-resident (~128 VGPR/lane).
__global__ __launch_bounds__(256, 2)
void node_rk4_kernel(const float* __restrict__ x0, const float* __restrict__ tarr,
                     const float* __restrict__ W1, const float* __restrict__ b1,
                     const float* __restrict__ W2, const float* __restrict__ b2,
                     float* __restrict__ out)
{
  __shared__ __align__(16) _Float16 Yh[16][YSTR];
  __shared__ __align__(16) _Float16 Hh[16][HSTR];

  const int tid  = threadIdx.x;
  const int w    = tid >> 6;        // wave 0..3
  const int lane = tid & 63;
  const int m    = lane & 15;
  const int g    = lane >> 4;       // 0..3
  const int row0 = (int)blockIdx.x * BM;

  // ---- weight fragments in registers (one-time) ----
  // intra-chunk K mapping: k = kk*32 + 8*g + j  (same for A and B -> safe)
  f16x8 wB1[4][4];   // [col-tile t][k-chunk kk], H col = 64w+16t+m
  f16x8 wB2[2][8];   // [col-tile t][k-chunk kk], K col = 32w+16t+m
#pragma unroll
  for (int t = 0; t < 4; ++t)
#pragma unroll
    for (int kk = 0; kk < 4; ++kk) {
      f16x8 v;
#pragma unroll
      for (int j = 0; j < 8; ++j)
        v[j] = (_Float16)W1[(kk*32 + 8*g + j)*256 + (64*w + 16*t + m)];
      wB1[t][kk] = v;
    }
#pragma unroll
  for (int t = 0; t < 2; ++t)
#pragma unroll
    for (int kk = 0; kk < 8; ++kk) {
      f16x8 v;
#pragma unroll
      for (int j = 0; j < 8; ++j)
        v[j] = (_Float16)W2[(kk*32 + 8*g + j)*128 + (32*w + 16*t + m)];
      wB2[t][kk] = v;
    }
  float bb1[4], bb2[2];
#pragma unroll
  for (int t = 0; t < 4; ++t) bb1[t] = b1[64*w + 16*t + m];
#pragma unroll
  for (int t = 0; t < 2; ++t) bb2[t] = b2[32*w + 16*t + m];

  const int c0 = 32*w + m;          // layer-2 output cols owned by this lane
  const int c1 = c0 + 16;

  // ---- per-lane fp32 state: rows 4g+i, cols {c0,c1} ----
  float y[2][4], k1[2][4], k2[2][4], k3[2][4], yn[2][4];
#pragma unroll
  for (int i = 0; i < 4; ++i) {
    float v0 = (c0 < 64) ? x0[(row0 + 4*g + i)*64 + c0] : 0.f;
    float v1 = (c1 < 64) ? x0[(row0 + 4*g + i)*64 + c1] : 0.f;
    y[0][i] = v0; yn[0][i] = v0;
    y[1][i] = v1; yn[1][i] = v1;
  }
  if (c0 < 64) {  // w<2: both c0,c1 < 64
#pragma unroll
    for (int i = 0; i < 4; ++i) {
      out[(row0 + 4*g + i)*64 + c0] = y[0][i];
      out[(row0 + 4*g + i)*64 + c1] = y[1][i];
    }
  }

  for (int step = 0; step < T_STEPS; ++step) {
    const float dt = vsub(tarr[step+1], tarr[step]);
    const float third = dt * (1.f/3.f);

#pragma unroll
    for (int stage = 0; stage < 4; ++stage) {
      // stage input -> LDS
#pragma unroll
      for (int i = 0; i < 4; ++i) {
        Yh[4*g + i][c0] = (_Float16)yn[0][i];
        Yh[4*g + i][c1] = (_Float16)yn[1][i];
      }
      __syncthreads();

      // layer 1: H = tanh(Y @ W1 + b1), 4 col-tiles per wave
      f32x4 acc[4];
#pragma unroll
      for (int t = 0; t < 4; ++t) acc[t] = (f32x4){ bb1[t], bb1[t], bb1[t], bb1[t] };
#pragma unroll
      for (int kk = 0; kk < 4; ++kk) {
        f16x8 a = ld_frag(&Yh[m][kk*32 + 8*g]);
#pragma unroll
        for (int t = 0; t < 4; ++t)
          acc[t] = __builtin_amdgcn_mfma_f32_16x16x32_f16(a, wB1[t][kk], acc[t], 0,0,0);
      }
#pragma unroll
      for (int t = 0; t < 4; ++t)
#pragma unroll
        for (int i = 0; i < 4; ++i)
          Hh[4*g + i][64*w + 16*t + m] = (_Float16)fast_tanh(acc[t][i]);
      __syncthreads();

      // layer 2: K = H @ W2 + b2, 2 col-tiles, split k-chains for ILP
      f32x4 accA[2], accB[2];
#pragma unroll
      for (int t = 0; t < 2; ++t) {
        accA[t] = (f32x4){ bb2[t], bb2[t], bb2[t], bb2[t] };
        accB[t] = (f32x4){ 0.f, 0.f, 0.f, 0.f };
      }
#pragma unroll
      for (int kk = 0; kk < 4; ++kk) {
        f16x8 aA = ld_frag(&Hh[m][kk*32 + 8*g]);
        f16x8 aB = ld_frag(&Hh[m][(kk+4)*32 + 8*g]);
#pragma unroll
        for (int t = 0; t < 2; ++t) {
          accA[t] = __builtin_amdgcn_mfma_f32_16x16x32_f16(aA, wB2[t][kk],   accA[t], 0,0,0);
          accB[t] = __builtin_amdgcn_mfma_f32_16x16x32_f16(aB, wB2[t][kk+4], accB[t], 0,0,0);
        }
      }

      // RK4 (3/8 rule) bookkeeping for both col-tiles
      if (stage == 0) {
#pragma unroll
        for (int t = 0; t < 2; ++t)
#pragma unroll
          for (int i = 0; i < 4; ++i) { k1[t][i] = accA[t][i]+accB[t][i]; yn[t][i] = y[t][i] + third*k1[t][i]; }
      } else if (stage == 1) {
#pragma unroll
        for (int t = 0; t < 2; ++t)
#pragma unroll
          for (int i = 0; i < 4; ++i) { k2[t][i] = accA[t][i]+accB[t][i]; yn[t][i] = y[t][i] + dt*(k2[t][i] - k1[t][i]*(1.f/3.f)); }
      } else if (stage == 2) {
#pragma unroll
        for (int t = 0; t < 2; ++t)
#pragma unroll
          for (int i = 0; i < 4; ++i) { k3[t][i] = accA[t][i]+accB[t][i]; yn[t][i] = y[t][i] + dt*(k1[t][i] - k2[t][i] + k3[t][i]); }
      } else {
#pragma unroll
        for (int t = 0; t < 2; ++t)
#pragma unroll
          for (int i = 0; i < 4; ++i) {
            float k4 = accA[t][i]+accB[t][i];
            y[t][i] += dt*0.125f*(k1[t][i] + 3.f*(k2[t][i]+k3[t][i]) + k4);
            yn[t][i] = y[t][i];
          }
        if (c0 < 64) {
#pragma unroll
          for (int i = 0; i < 4; ++i) {
            out[(step+1)*OUTSTRIDE + (row0 + 4*g + i)*64 + c0] = y[0][i];
            out[(step+1)*OUTSTRIDE + (row0 + 4*g + i)*64 + c1] = y[1][i];
          }
        }
      }
    }
  }
}

extern "C" void kernel_launch(void* const* d_in, const int* in_sizes, int n_in,
                              void* d_out, int out_size, void* d_ws, size_t ws_size,
                              hipStream_t stream) {
  const float* x0 = (const float*)d_in[0];
  const float* t  = (const float*)d_in[1];
  const float* W1 = (const float*)d_in[2];
  const float* b1 = (const float*)d_in[3];
  const float* W2 = (const float*)d_in[4];
  const float* b2 = (const float*)d_in[5];
  float* out = (float*)d_out;
  hipLaunchKernelGGL(node_rk4_kernel, dim3(4096/BM), dim3(256), 0, stream,
                     x0, t, W1, b1, W2, b2, out);
}

// Round 8
// 151.645 us; speedup vs baseline: 1.3882x; 1.3882x over previous
//
#include <hip/hip_runtime.h>

typedef __attribute__((ext_vector_type(8))) _Float16 f16x8;
typedef __attribute__((ext_vector_type(4))) _Float16 f16x4;
typedef __attribute__((ext_vector_type(4))) float f32x4;

#define T_STEPS 49
#define BM 16
#define OUTSTRIDE (4096*64)
#define YSTR 132   // f16/row: 264B = 66 dw == 2 mod 8 (kept from R5; reads measured conflict-free)
#define HSTR 260   // f16/row: 520B = 130 dw == 2 mod 8

__device__ __forceinline__ float fast_tanh(float x) {
  float e = __builtin_amdgcn_exp2f(x * 2.885390081777927f);
  return 1.f - 2.f * __builtin_amdgcn_rcpf(e + 1.f);
}
__device__ __forceinline__ f16x8 ld_frag(const _Float16* p) {
  f16x4 a = *(const f16x4*)p;        // rows 8B-aligned
  f16x4 b = *(const f16x4*)(p + 4);
  return __builtin_shufflevector(a, b, 0,1,2,3,4,5,6,7);
}
// Backend bug workaround: v-op with two SGPR sources violates constant-bus rule.
__device__ __forceinline__ float vsub(float a, float b) {
  float r;
  asm("v_sub_f32 %0, %1, %2" : "=v"(r) : "v"(a), "v"(b));
  return r;
}

// 8-wave WG, BM=16 rows, grid 256 = 1 WG/CU (R5 structure). NEW vs R5: both
// MFMAs are operand-SWAPPED — mfma(W, Y) computes the TRANSPOSED output tile,
// so each lane holds (row m, 4 consecutive cols). LDS writes become packed
// ds_write_b64 (Y: 1, H: 2 per lane, was 12 x b16), and x0/out go via float4.
// Weight register contents and all LDS reads are bit-identical to R5.
__global__ __launch_bounds__(512)
void node_rk4_kernel(const float* __restrict__ x0, const float* __restrict__ tarr,
                     const float* __restrict__ W1, const float* __restrict__ b1,
                     const float* __restrict__ W2, const float* __restrict__ b2,
                     float* __restrict__ out)
{
  __shared__ __align__(16) _Float16 Yh[16][YSTR];
  __shared__ __align__(16) _Float16 Hh[16][HSTR];

  const int tid  = threadIdx.x;
  const int w    = tid >> 6;        // wave 0..7
  const int lane = tid & 63;
  const int m    = lane & 15;       // batch row owned by this lane (output side)
  const int g    = lane >> 4;       // 0..3
  const int row0 = (int)blockIdx.x * BM;

  // ---- weight fragments in registers (identical packing to R5) ----
  // intra-chunk K mapping: k = kk*32 + 8*g + j (same wiring for A and B -> the
  // assumed mapping cancels; only the HW-verified C/D layout matters)
  f16x8 wB1[2][4], wB2[8];
#pragma unroll
  for (int c = 0; c < 2; ++c)
#pragma unroll
    for (int kk = 0; kk < 4; ++kk) {
      f16x8 v;
#pragma unroll
      for (int j = 0; j < 8; ++j)
        v[j] = (_Float16)W1[(kk*32 + 8*g + j)*256 + (32*w + 16*c + m)];
      wB1[c][kk] = v;
    }
#pragma unroll
  for (int kk = 0; kk < 8; ++kk) {
    f16x8 v;
#pragma unroll
    for (int j = 0; j < 8; ++j)
      v[j] = (_Float16)W2[(kk*32 + 8*g + j)*128 + (16*w + m)];
    wB2[kk] = v;
  }
  // biases: transposed D-frag -> per-reg bias (row index 4g+i of the tile)
  f32x4 bb1[2], bb2v;
#pragma unroll
  for (int c = 0; c < 2; ++c)
#pragma unroll
    for (int i = 0; i < 4; ++i) bb1[c][i] = b1[16*(2*w + c) + 4*g + i];
#pragma unroll
  for (int i = 0; i < 4; ++i) bb2v[i] = b2[16*w + 4*g + i];

  // ---- per-lane fp32 state: batch row m, ycols ccol..ccol+3 ----
  const int ccol = 16*w + 4*g;
  float y[4], k1[4], k2[4], k3[4], yn[4];
  if (ccol < 64) {
    const float4 v = *(const float4*)&x0[(row0 + m)*64 + ccol];
    y[0]=v.x; y[1]=v.y; y[2]=v.z; y[3]=v.w;
  } else {
    y[0]=y[1]=y[2]=y[3]=0.f;
  }
#pragma unroll
  for (int i = 0; i < 4; ++i) yn[i] = y[i];
  if (ccol < 64) {   // sol[0] = x0
    float4 v; v.x=y[0]; v.y=y[1]; v.z=y[2]; v.w=y[3];
    *(float4*)&out[(row0 + m)*64 + ccol] = v;
  }
  // initial Y -> LDS (packed b64)
  {
    f16x4 p;
#pragma unroll
    for (int i = 0; i < 4; ++i) p[i] = (_Float16)yn[i];
    *(f16x4*)&Yh[m][ccol] = p;
  }
  __syncthreads();

  for (int step = 0; step < T_STEPS; ++step) {
    const float dt = vsub(tarr[step+1], tarr[step]);
    const float third = dt * (1.f/3.f);

#pragma unroll
    for (int stage = 0; stage < 4; ++stage) {
      // layer 1 (swapped): acc[c] = (Y @ W1)^T tile 2w+c -> lane holds H[m][16(2w+c)+4g+i]
      f32x4 acc0 = bb1[0], acc1 = bb1[1];
#pragma unroll
      for (int kk = 0; kk < 4; ++kk) {
        f16x8 a = ld_frag(&Yh[m][kk*32 + 8*g]);
        acc0 = __builtin_amdgcn_mfma_f32_16x16x32_f16(wB1[0][kk], a, acc0, 0,0,0);
        acc1 = __builtin_amdgcn_mfma_f32_16x16x32_f16(wB1[1][kk], a, acc1, 0,0,0);
      }
      {
        f16x4 p0, p1;
#pragma unroll
        for (int i = 0; i < 4; ++i) { p0[i] = (_Float16)fast_tanh(acc0[i]); p1[i] = (_Float16)fast_tanh(acc1[i]); }
        *(f16x4*)&Hh[m][16*(2*w+0) + 4*g] = p0;
        *(f16x4*)&Hh[m][16*(2*w+1) + 4*g] = p1;
      }
      __syncthreads();

      // layer 2 (swapped): lane holds K[m][16w+4g+i]
      f32x4 accA = bb2v;
      f32x4 accB = { 0.f, 0.f, 0.f, 0.f };
#pragma unroll
      for (int kk = 0; kk < 4; ++kk) {
        f16x8 aA = ld_frag(&Hh[m][kk*32 + 8*g]);
        f16x8 aB = ld_frag(&Hh[m][(kk+4)*32 + 8*g]);
        accA = __builtin_amdgcn_mfma_f32_16x16x32_f16(wB2[kk],   aA, accA, 0,0,0);
        accB = __builtin_amdgcn_mfma_f32_16x16x32_f16(wB2[kk+4], aB, accB, 0,0,0);
      }

      // RK4 (3/8 rule) bookkeeping
      if (stage == 0) {
#pragma unroll
        for (int i = 0; i < 4; ++i) { k1[i] = accA[i]+accB[i]; yn[i] = y[i] + third*k1[i]; }
      } else if (stage == 1) {
#pragma unroll
        for (int i = 0; i < 4; ++i) { k2[i] = accA[i]+accB[i]; yn[i] = y[i] + dt*(k2[i] - k1[i]*(1.f/3.f)); }
      } else if (stage == 2) {
#pragma unroll
        for (int i = 0; i < 4; ++i) { k3[i] = accA[i]+accB[i]; yn[i] = y[i] + dt*(k1[i] - k2[i] + k3[i]); }
      } else {
#pragma unroll
        for (int i = 0; i < 4; ++i) {
          float k4 = accA[i]+accB[i];
          y[i] += dt*0.125f*(k1[i] + 3.f*(k2[i]+k3[i]) + k4);
          yn[i] = y[i];
        }
        if (ccol < 64) {
          float4 v; v.x=y[0]; v.y=y[1]; v.z=y[2]; v.w=y[3];
          *(float4*)&out[(size_t)(step+1)*OUTSTRIDE + (row0 + m)*64 + ccol] = v;
        }
      }
      // next stage input -> LDS (packed b64)
      {
        f16x4 p;
#pragma unroll
        for (int i = 0; i < 4; ++i) p[i] = (_Float16)yn[i];
        *(f16x4*)&Yh[m][ccol] = p;
      }
      __syncthreads();
    }
  }
}

extern "C" void kernel_launch(void* const* d_in, const int* in_sizes, int n_in,
                              void* d_out, int out_size, void* d_ws, size_t ws_size,
                              hipStream_t stream) {
  const float* x0 = (const float*)d_in[0];
  const float* t  = (const float*)d_in[1];
  const float* W1 = (const float*)d_in[2];
  const float* b1 = (const float*)d_in[3];
  const float* W2 = (const float*)d_in[4];
  const float* b2 = (const float*)d_in[5];
  float* out = (float*)d_out;
  hipLaunchKernelGGL(node_rk4_kernel, dim3(4096/BM), dim3(512), 0, stream,
                     x0, t, W1, b1, W2, b2, out);
}

// Round 12
// 150.110 us; speedup vs baseline: 1.4024x; 1.0102x over previous
//
#include <hip/hip_runtime.h>

typedef __attribute__((ext_vector_type(8))) _Float16 f16x8;
typedef __attribute__((ext_vector_type(4))) _Float16 f16x4;
typedef __attribute__((ext_vector_type(2))) _Float16 f16x2;
typedef __attribute__((ext_vector_type(4))) float f32x4;
typedef __attribute__((ext_vector_type(2))) float f32x2;

#define T_STEPS 49
#define BM 16
#define OUTSTRIDE (4096*64)
#define YSTR 132   // f16/row: 264B = 66 dw == 2 mod 8 (write-conflict-free, measured 0)
#define HSTR 260   // f16/row: 520B = 130 dw == 2 mod 8

__device__ __forceinline__ f16x8 ld_frag(const _Float16* p) {
  f16x4 a = *(const f16x4*)p;        // rows 8B-aligned
  f16x4 b = *(const f16x4*)(p + 4);
  return __builtin_shufflevector(a, b, 0,1,2,3,4,5,6,7);
}
// Backend bug workaround: v-op with two SGPR sources violates constant-bus rule.
__device__ __forceinline__ float vsub(float a, float b) {
  float r;
  asm("v_sub_f32 %0, %1, %2" : "=v"(r) : "v"(a), "v"(b));
  return r;
}
// Packed f32 arithmetic via NATIVE vector ops — ISel emits v_pk_{add,mul,fma}_f32
// with correct op_sel/op_sel_hi. (R10/R11 lesson: hand-written VOP3P asm silently
// miscomputed the hi half; never hand-encode VOP3P.)
__device__ __forceinline__ f32x2 vfma2(f32x2 a, f32x2 b, f32x2 c) {
  return __builtin_elementwise_fma(a, b, c);
}
// packed tanh on a pair
__device__ __forceinline__ f32x2 tanh2(f32x2 x) {
  const f32x2 c2  = { 2.885390081777927f, 2.885390081777927f };
  const f32x2 one = { 1.f, 1.f };
  const f32x2 m2  = { -2.f, -2.f };
  f32x2 t = x * c2;
  f32x2 e;
  e[0] = __builtin_amdgcn_exp2f(t[0]);
  e[1] = __builtin_amdgcn_exp2f(t[1]);
  f32x2 ep1 = e + one;
  f32x2 r;
  r[0] = __builtin_amdgcn_rcpf(ep1[0]);
  r[1] = __builtin_amdgcn_rcpf(ep1[1]);
  return vfma2(r, m2, one);           // 1 - 2/(e^{2x}+1)
}
__device__ __forceinline__ f16x4 cvt4(f32x2 a, f32x2 b) {
  f16x2 h0 = __builtin_bit_cast(f16x2, __builtin_amdgcn_cvt_pkrtz(a[0], a[1]));
  f16x2 h1 = __builtin_bit_cast(f16x2, __builtin_amdgcn_cvt_pkrtz(b[0], b[1]));
  return __builtin_shufflevector(h0, h1, 0,1,2,3);
}

// 8-wave WG, BM=16 rows, grid 256 = 1 WG/CU. R8 structure (swapped-operand
// MFMAs, packed b64 LDS writes) + packed f32x2 per-lane arithmetic via native
// vector IR (compiler-encoded VOP3P) + packed f16 converts.
__global__ __launch_bounds__(512)
void node_rk4_kernel(const float* __restrict__ x0, const float* __restrict__ tarr,
                     const float* __restrict__ W1, const float* __restrict__ b1,
                     const float* __restrict__ W2, const float* __restrict__ b2,
                     float* __restrict__ out)
{
  __shared__ __align__(16) _Float16 Yh[16][YSTR];
  __shared__ __align__(16) _Float16 Hh[16][HSTR];

  const int tid  = threadIdx.x;
  const int w    = tid >> 6;        // wave 0..7
  const int lane = tid & 63;
  const int m    = lane & 15;       // batch row owned by this lane (output side)
  const int g    = lane >> 4;       // 0..3
  const int row0 = (int)blockIdx.x * BM;

  // ---- weight fragments in registers (identical packing to R8) ----
  f16x8 wB1[2][4], wB2[8];
#pragma unroll
  for (int c = 0; c < 2; ++c)
#pragma unroll
    for (int kk = 0; kk < 4; ++kk) {
      f16x8 v;
#pragma unroll
      for (int j = 0; j < 8; ++j)
        v[j] = (_Float16)W1[(kk*32 + 8*g + j)*256 + (32*w + 16*c + m)];
      wB1[c][kk] = v;
    }
#pragma unroll
  for (int kk = 0; kk < 8; ++kk) {
    f16x8 v;
#pragma unroll
    for (int j = 0; j < 8; ++j)
      v[j] = (_Float16)W2[(kk*32 + 8*g + j)*128 + (16*w + m)];
    wB2[kk] = v;
  }
  // biases: transposed D-frag -> per-reg bias (row index 4g+i of the tile)
  f32x4 bb1[2], bb2v;
#pragma unroll
  for (int c = 0; c < 2; ++c)
#pragma unroll
    for (int i = 0; i < 4; ++i) bb1[c][i] = b1[16*(2*w + c) + 4*g + i];
#pragma unroll
  for (int i = 0; i < 4; ++i) bb2v[i] = b2[16*w + 4*g + i];

  // ---- per-lane fp32 state as f32x2 pairs: batch row m, ycols ccol..ccol+3 ----
  const int ccol = 16*w + 4*g;
  f32x2 y[2], k1[2], k2[2], k3[2], yn[2];
  if (ccol < 64) {
    const float4 v = *(const float4*)&x0[(row0 + m)*64 + ccol];
    y[0][0]=v.x; y[0][1]=v.y; y[1][0]=v.z; y[1][1]=v.w;
  } else {
    y[0] = (f32x2){0.f,0.f}; y[1] = (f32x2){0.f,0.f};
  }
  yn[0] = y[0]; yn[1] = y[1];
  if (ccol < 64) {   // sol[0] = x0
    float4 v; v.x=y[0][0]; v.y=y[0][1]; v.z=y[1][0]; v.w=y[1][1];
    *(float4*)&out[(row0 + m)*64 + ccol] = v;
  }
  *(f16x4*)&Yh[m][ccol] = cvt4(yn[0], yn[1]);
  __syncthreads();

  for (int step = 0; step < T_STEPS; ++step) {
    const float dt = vsub(tarr[step+1], tarr[step]);
    const f32x2 dt2      = { dt, dt };
    const f32x2 third2   = { dt*(1.f/3.f), dt*(1.f/3.f) };
    const f32x2 mthird2  = { -1.f/3.f, -1.f/3.f };
    const f32x2 three2   = { 3.f, 3.f };
    const f32x2 dt8      = { dt*0.125f, dt*0.125f };

#pragma unroll
    for (int stage = 0; stage < 4; ++stage) {
      // layer 1 (swapped): lane holds H[m][16(2w+c)+4g+i]
      f32x4 acc0 = bb1[0], acc1 = bb1[1];
#pragma unroll
      for (int kk = 0; kk < 4; ++kk) {
        f16x8 a = ld_frag(&Yh[m][kk*32 + 8*g]);
        acc0 = __builtin_amdgcn_mfma_f32_16x16x32_f16(wB1[0][kk], a, acc0, 0,0,0);
        acc1 = __builtin_amdgcn_mfma_f32_16x16x32_f16(wB1[1][kk], a, acc1, 0,0,0);
      }
      {
        f32x2 t00 = tanh2((f32x2){acc0[0], acc0[1]});
        f32x2 t01 = tanh2((f32x2){acc0[2], acc0[3]});
        f32x2 t10 = tanh2((f32x2){acc1[0], acc1[1]});
        f32x2 t11 = tanh2((f32x2){acc1[2], acc1[3]});
        *(f16x4*)&Hh[m][16*(2*w+0) + 4*g] = cvt4(t00, t01);
        *(f16x4*)&Hh[m][16*(2*w+1) + 4*g] = cvt4(t10, t11);
      }
      __syncthreads();

      // layer 2 (swapped): lane holds K[m][16w+4g+i]
      f32x4 accA = bb2v;
      f32x4 accB = { 0.f, 0.f, 0.f, 0.f };
#pragma unroll
      for (int kk = 0; kk < 4; ++kk) {
        f16x8 aA = ld_frag(&Hh[m][kk*32 + 8*g]);
        f16x8 aB = ld_frag(&Hh[m][(kk+4)*32 + 8*g]);
        accA = __builtin_amdgcn_mfma_f32_16x16x32_f16(wB2[kk],   aA, accA, 0,0,0);
        accB = __builtin_amdgcn_mfma_f32_16x16x32_f16(wB2[kk+4], aB, accB, 0,0,0);
      }
      f32x2 ks[2];
      ks[0] = (f32x2){accA[0],accA[1]} + (f32x2){accB[0],accB[1]};
      ks[1] = (f32x2){accA[2],accA[3]} + (f32x2){accB[2],accB[3]};

      // RK4 (3/8 rule) bookkeeping, packed via native vector ops
      if (stage == 0) {
#pragma unroll
        for (int p = 0; p < 2; ++p) { k1[p] = ks[p]; yn[p] = vfma2(k1[p], third2, y[p]); }
      } else if (stage == 1) {
#pragma unroll
        for (int p = 0; p < 2; ++p) {
          k2[p] = ks[p];
          f32x2 a = vfma2(k1[p], mthird2, k2[p]);    // k2 - k1/3
          yn[p] = vfma2(a, dt2, y[p]);
        }
      } else if (stage == 2) {
#pragma unroll
        for (int p = 0; p < 2; ++p) {
          k3[p] = ks[p];
          f32x2 b = (k1[p] - k2[p]) + k3[p];
          yn[p] = vfma2(b, dt2, y[p]);
        }
      } else {
#pragma unroll
        for (int p = 0; p < 2; ++p) {
          f32x2 s1 = k2[p] + k3[p];
          f32x2 s2 = vfma2(s1, three2, k1[p]);       // k1 + 3(k2+k3)
          f32x2 s3 = s2 + ks[p];                     // + k4
          y[p] = vfma2(s3, dt8, y[p]);
          yn[p] = y[p];
        }
        if (ccol < 64) {
          float4 v; v.x=y[0][0]; v.y=y[0][1]; v.z=y[1][0]; v.w=y[1][1];
          *(float4*)&out[(size_t)(step+1)*OUTSTRIDE + (row0 + m)*64 + ccol] = v;
        }
      }
      // next stage input -> LDS (packed b64)
      *(f16x4*)&Yh[m][ccol] = cvt4(yn[0], yn[1]);
      __syncthreads();
    }
  }
}

extern "C" void kernel_launch(void* const* d_in, const int* in_sizes, int n_in,
                              void* d_out, int out_size, void* d_ws, size_t ws_size,
                              hipStream_t stream) {
  const float* x0 = (const float*)d_in[0];
  const float* t  = (const float*)d_in[1];
  const float* W1 = (const float*)d_in[2];
  const float* b1 = (const float*)d_in[3];
  const float* W2 = (const float*)d_in[4];
  const float* b2 = (const float*)d_in[5];
  float* out = (float*)d_out;
  hipLaunchKernelGGL(node_rk4_kernel, dim3(4096/BM), dim3(512), 0, stream,
                     x0, t, W1, b1, W2, b2, out);
}